// Round 3
// baseline (201.803 us; speedup 1.0000x reference)
//
#include <hip/hip_runtime.h>

// YOLOv1 loss, S=14, B=2, C=20, 30 fp32 channels/cell, 802816 cells.
// Memory-bound. Per-wave LDS staging with a SINGLE reused buffer:
//   coalesced-load pred tile -> LDS -> regs, then target tile -> same LDS -> regs.
// 7680 B/wave LDS (30720/block) -> 5 blocks/CU -> 20 waves/CU.
// 802816 = 3136 blocks x 256 threads exactly (no tail).

__global__ void zero_out_kernel(float* out) { out[0] = 0.0f; }

__global__ __launch_bounds__(256, 5) void yolo_loss_kernel(
    const float* __restrict__ pred, const float* __restrict__ target,
    float* __restrict__ out)
{
    __shared__ float stage[4][1920];   // 4 waves x (64 cells x 30 ch); reused for pred then target

    const int lane = threadIdx.x & 63;
    const int wid  = threadIdx.x >> 6;
    const size_t tile0 = ((size_t)blockIdx.x * 4 + wid) * 64;
    const float* gp = pred   + tile0 * 30;
    const float* gt = target + tile0 * 30;

    float*  sw  = stage[wid];
    float4* sw4 = (float4*)sw;
    float2* sw2 = (float2*)sw;

    // ---- pred: global -> regs (coalesced: 7x dwordx4 + 1x dwordx2)
    float4 rp4[7];
    const float4* gp4 = (const float4*)gp;
    #pragma unroll
    for (int i = 0; i < 7; ++i) rp4[i] = gp4[i*64 + lane];
    float2 rp2 = ((const float2*)gp)[896 + lane];

    // ---- pred: regs -> LDS (identity copy)
    #pragma unroll
    for (int i = 0; i < 7; ++i) sw4[i*64 + lane] = rp4[i];
    sw2[896 + lane] = rp2;

    // ---- target: issue global loads now so they fly during pred LDS reads
    float4 rt4[7];
    const float4* gt4 = (const float4*)gt;
    #pragma unroll
    for (int i = 0; i < 7; ++i) rt4[i] = gt4[i*64 + lane];
    float2 rt2 = ((const float2*)gt)[896 + lane];

    // ---- pred: LDS -> own cell's 30 floats (wave-private, DS in-order: no barrier)
    float pv[30];
    {
        const float2* rp = (const float2*)&sw[lane * 30];
        #pragma unroll
        for (int j = 0; j < 15; ++j) {
            float2 a = rp[j]; pv[2*j] = a.x; pv[2*j+1] = a.y;
        }
    }

    // ---- target: regs -> same LDS buffer (DS ops per-wave in-order; reads above
    //      have already captured their data before these writes execute)
    #pragma unroll
    for (int i = 0; i < 7; ++i) sw4[i*64 + lane] = rt4[i];
    sw2[896 + lane] = rt2;

    // ---- target: LDS -> 25 needed floats (ch 5..9 duplicate ch 0..4)
    float t0, t1, t2v, t3, t4;
    float tcls[20];
    {
        const float* tb = &sw[lane * 30];
        float2 a = *(const float2*)(tb + 0);
        float2 b = *(const float2*)(tb + 2);
        t0 = a.x; t1 = a.y; t2v = b.x; t3 = b.y;
        t4 = tb[4];
        const float2* tc = (const float2*)(tb + 10);
        #pragma unroll
        for (int j = 0; j < 10; ++j) {
            float2 c = tc[j]; tcls[2*j] = c.x; tcls[2*j+1] = c.y;
        }
    }

    // ---- per-cell loss (same math as verified round-1 kernel)
    const float invS = 1.0f / 14.0f;
    const bool obj = t4 > 0.0f;

    float tcx = t0 * invS, tcy = t1 * invS;
    float thw = 0.5f * t2v, thh = 0.5f * t3;
    float tx1 = tcx - thw, ty1 = tcy - thh;
    float tx2 = tcx + thw, ty2 = tcy + thh;
    float area_t = (tx2 - tx1) * (ty2 - ty1);

    float iou0 = 0.0f, iou1 = 0.0f;
    #pragma unroll
    for (int b = 0; b < 2; ++b) {
        float cx = pv[5*b + 0] * invS, cy = pv[5*b + 1] * invS;
        float hw = 0.5f * pv[5*b + 2], hh = 0.5f * pv[5*b + 3];
        float x1 = cx - hw, y1 = cy - hh, x2 = cx + hw, y2 = cy + hh;
        float lx = fmaxf(x1, tx1), ly = fmaxf(y1, ty1);
        float rx = fminf(x2, tx2), ry = fminf(y2, ty2);
        float w = fmaxf(rx - lx, 0.0f), h = fmaxf(ry - ly, 0.0f);
        float inter = w * h;
        float area_p = (x2 - x1) * (y2 - y1);
        float iou = inter / (area_p + area_t - inter);
        if (b == 0) iou0 = iou; else iou1 = iou;
    }
    const bool  sel     = iou1 > iou0;          // jnp.argmax: first max wins
    const float max_iou = fmaxf(iou0, iou1);

    float local;
    if (obj) {
        float pbx = sel ? pv[5] : pv[0];
        float pby = sel ? pv[6] : pv[1];
        float pbw = sel ? pv[7] : pv[2];
        float pbh = sel ? pv[8] : pv[3];
        float pbc = sel ? pv[9] : pv[4];

        float dx = pbx - t0, dy = pby - t1;
        float loss_xy = dx*dx + dy*dy;

        float sws = sqrtf(pbw) - sqrtf(t2v);
        float shs = sqrtf(pbh) - sqrtf(t3);
        float loss_wh = sws*sws + shs*shs;

        float dob = pbc - max_iou;
        float loss_obj = dob * dob;

        float loss_cls = 0.0f;
        #pragma unroll
        for (int c = 0; c < 20; ++c) {
            float d = pv[10 + c] - tcls[c];
            loss_cls = fmaf(d, d, loss_cls);
        }
        local = 5.0f * (loss_xy + loss_wh) + loss_obj + loss_cls;
    } else {
        // noobj: target conf == t4 for both tiled boxes (t4 <= 0 here)
        float d0 = pv[4] - t4;
        float d1 = pv[9] - t4;
        local = 0.5f * (d0*d0 + d1*d1);
    }

    // ---- wave-64 shuffle reduction -> block -> one atomic
    #pragma unroll
    for (int off = 32; off > 0; off >>= 1)
        local += __shfl_down(local, off, 64);

    __shared__ float wsum[4];
    if (lane == 0) wsum[wid] = local;
    __syncthreads();
    if (threadIdx.x == 0) {
        float s = wsum[0] + wsum[1] + wsum[2] + wsum[3];
        atomicAdd(out, s * (1.0f / 4096.0f));
    }
}

extern "C" void kernel_launch(void* const* d_in, const int* in_sizes, int n_in,
                              void* d_out, int out_size, void* d_ws, size_t ws_size,
                              hipStream_t stream) {
    const float* pred   = (const float*)d_in[0];
    const float* target = (const float*)d_in[1];
    float* out = (float*)d_out;

    zero_out_kernel<<<1, 1, 0, stream>>>(out);
    yolo_loss_kernel<<<3136, 256, 0, stream>>>(pred, target, out);
}